// Round 4
// baseline (205.069 us; speedup 1.0000x reference)
//
#include <hip/hip_runtime.h>
#include <hip/hip_bf16.h>

#define BTC 16
#define NC 1024
#define DC 128
#define HC 8
#define HDC 16

typedef __attribute__((ext_vector_type(8))) short bf16x8;   // 8 bf16 = 4 VGPR
typedef __attribute__((ext_vector_type(4))) float f32x4;    // MFMA C/D frag 16x16
typedef __attribute__((ext_vector_type(4))) short short4v;  // 4 bf16 = 2 VGPR

#if __has_builtin(__builtin_amdgcn_exp2f)
#define EXP2F(x) __builtin_amdgcn_exp2f(x)
#else
#define EXP2F(x) exp2f(x)
#endif

// q scale: 0.25 (1/sqrt(HD)) * log2(e)  -> attention uses exp2 directly
#define QSCALE 0.36067376022224085f

union PK2 { short4v s4; __hip_bfloat162 h2[2]; };
union PK8 { bf16x8 v; short s[8]; __hip_bfloat162 h2[4]; };

static __device__ inline short f2bf(float f) {               // RNE f32->bf16
    unsigned u = __builtin_bit_cast(unsigned, f);
    u += 0x7fffu + ((u >> 16) & 1u);
    return (short)(u >> 16);
}

// 16x16x16 bf16 MFMA (K = 16 = head dim, no zero padding)
static __device__ inline f32x4 qkmfma(short4v a, short4v b, f32x4 c) {
#if __has_builtin(__builtin_amdgcn_mfma_f32_16x16x16bf16_1k)
    return __builtin_amdgcn_mfma_f32_16x16x16bf16_1k(a, b, c, 0, 0, 0);
#elif __has_builtin(__builtin_amdgcn_mfma_f32_16x16x16_bf16)
    return __builtin_amdgcn_mfma_f32_16x16x16_bf16(a, b, c, 0, 0, 0);
#else
    // zero-pad both operands into matching K-slots of the K=32 op
    bf16x8 a8 = {a[0], a[1], a[2], a[3], 0, 0, 0, 0};
    bf16x8 b8 = {b[0], b[1], b[2], b[3], 0, 0, 0, 0};
    return __builtin_amdgcn_mfma_f32_16x16x32_bf16(a8, b8, c, 0, 0, 0);
#endif
}

// raw workgroup barrier: LDS-visibility only (lgkmcnt), keeps global register
// prefetches (vmcnt) in flight across the barrier (unlike __syncthreads).
#define LDS_BARRIER()                                              \
    do {                                                           \
        asm volatile("s_waitcnt lgkmcnt(0)" ::: "memory");         \
        __builtin_amdgcn_s_barrier();                              \
        asm volatile("" ::: "memory");                             \
    } while (0)

// ---------------- prep: fp32 -> bf16 for x and the 4 weight matrices --------
__global__ __launch_bounds__(256)
void prep_kernel(const float* __restrict__ x,
                 const float* __restrict__ Wq, const float* __restrict__ Wk,
                 const float* __restrict__ Wv, const float* __restrict__ Wo,
                 short* __restrict__ xbf, short* __restrict__ Wbf)
{
    int gid  = blockIdx.x * 256 + threadIdx.x;
    int base = gid * 4;
    const float* src;
    short* dst;
    if (base < 2097152) {                      // x: 16*1024*128
        src = x + base; dst = xbf + base;
    } else {
        int idx = base - 2097152;              // 0..65535 over 4 W's
        int w   = idx >> 14;
        int off = idx & 16383;
        src = ((w == 0) ? Wq : (w == 1) ? Wk : (w == 2) ? Wv : Wo) + off;
        dst = Wbf + w * 16384 + off;
    }
    float4 v = *(const float4*)src;
    PK2 pk;
    pk.h2[0] = __float22bfloat162_rn(make_float2(v.x, v.y));
    pk.h2[1] = __float22bfloat162_rn(make_float2(v.z, v.w));
    *(short4v*)dst = pk.s4;
}

// ---------------- MFMA projection, C = X @ W^T + b --------------------------
// block = 256 thr (4 waves), wave = 16 rows x 128 cols, K-loop 4x32.
// y = 0: q (scale QSCALE), 1: k — BOTH stored head-packed [bt][h][n][16].
// y = 2: v stored transposed AND key-permuted vt[bt][d][n'] where within each
//        32-key tile, key g*16+quad*4+r sits at n' = quad*8+g*4+r. This makes
//        the attention PV B-frag one contiguous b128 AND lets P be written to
//        LDS as one b128 per tile.
__global__ __launch_bounds__(256)
void proj_qkv(const short* __restrict__ xbf, const short* __restrict__ Wbf,
              const float* __restrict__ bq, const float* __restrict__ bk,
              const float* __restrict__ bv,
              short* __restrict__ qo, short* __restrict__ ko, short* __restrict__ vto)
{
    __shared__ short T[128 * 72];        // 18.4 KB transpose tile (y==2 only)

    const int y = blockIdx.y;
    const short* W = Wbf + y * 16384;
    const float* bias = (y == 0) ? bq : (y == 1) ? bk : bv;
    const float scale = (y == 0) ? QSCALE : 1.0f;

    const int tid  = threadIdx.x;
    const int wave = tid >> 6;
    const int lane = tid & 63;
    const int l15  = lane & 15;
    const int quad = lane >> 4;
    const int rowA = blockIdx.x * 64 + wave * 16;

    f32x4 acc[8];
#pragma unroll
    for (int t = 0; t < 8; ++t) acc[t] = (f32x4){0.f, 0.f, 0.f, 0.f};

#pragma unroll
    for (int kk = 0; kk < DC; kk += 32) {
        bf16x8 Af = *(const bf16x8*)&xbf[(size_t)(rowA + l15) * DC + kk + quad * 8];
#pragma unroll
        for (int t = 0; t < 8; ++t) {
            bf16x8 Bf = *(const bf16x8*)&W[(t * 16 + l15) * DC + kk + quad * 8];
            acc[t] = __builtin_amdgcn_mfma_f32_16x16x32_bf16(Af, Bf, acc[t], 0, 0, 0);
        }
    }

    if (y == 2) {
        // transpose through LDS: T[c][local_row], row stride 72 shorts
#pragma unroll
        for (int t = 0; t < 8; ++t) {
            int c = t * 16 + l15;
            float b = bias[c];
            PK2 pk;
            pk.h2[0] = __float22bfloat162_rn(make_float2(acc[t][0] + b, acc[t][1] + b));
            pk.h2[1] = __float22bfloat162_rn(make_float2(acc[t][2] + b, acc[t][3] + b));
            *(short4v*)&T[c * 72 + wave * 16 + quad * 4] = pk.s4;
        }
        __syncthreads();                  // y uniform per block: no divergence
        const int bt = blockIdx.x >> 4;
        const int n0 = (blockIdx.x * 64) & 1023;
        const int chunk = tid & 7;        // 8 chunks x 16 B = one 128-B d-row
        const int dr    = tid >> 3;       // 0..31
        const int tb    = (chunk >> 2) * 32 + (chunk & 3) * 4;  // permuted src
#pragma unroll
        for (int rep = 0; rep < 4; ++rep) {
            int d = rep * 32 + dr;
            PK8 u;
            *(short4v*)&u.s[0] = *(const short4v*)&T[d * 72 + tb];
            *(short4v*)&u.s[4] = *(const short4v*)&T[d * 72 + tb + 16];
            *(bf16x8*)&vto[((size_t)bt * DC + d) * NC + n0 + chunk * 8] = u.v;
        }
    } else {
        short* dst = (y == 0) ? qo : ko;
#pragma unroll
        for (int t = 0; t < 8; ++t) {
            int c  = t * 16 + l15;
            int hh = c >> 4, dd = c & 15;
            float b = bias[c];
#pragma unroll
            for (int r = 0; r < 4; ++r) {
                int row = rowA + quad * 4 + r;       // = bt*1024 + n
                int btq = row >> 10, n = row & 1023;
                float val = (acc[t][r] + b) * scale;
                dst[(((size_t)btq * HC + hh) * NC + n) * HDC + dd] = f2bf(val);
            }
        }
    }
}

// out-projection: bf16 ctx in, fp32 out
__global__ __launch_bounds__(256)
void proj_out(const short* __restrict__ cbf, const short* __restrict__ Wobf,
              const float* __restrict__ bo, float* __restrict__ out)
{
    const int tid  = threadIdx.x;
    const int wave = tid >> 6;
    const int lane = tid & 63;
    const int l15  = lane & 15;
    const int quad = lane >> 4;
    const int rowA = blockIdx.x * 64 + wave * 16;

    f32x4 acc[8];
#pragma unroll
    for (int t = 0; t < 8; ++t) acc[t] = (f32x4){0.f, 0.f, 0.f, 0.f};

#pragma unroll
    for (int kk = 0; kk < DC; kk += 32) {
        bf16x8 Af = *(const bf16x8*)&cbf[(size_t)(rowA + l15) * DC + kk + quad * 8];
#pragma unroll
        for (int t = 0; t < 8; ++t) {
            bf16x8 Bf = *(const bf16x8*)&Wobf[(t * 16 + l15) * DC + kk + quad * 8];
            acc[t] = __builtin_amdgcn_mfma_f32_16x16x32_bf16(Af, Bf, acc[t], 0, 0, 0);
        }
    }

#pragma unroll
    for (int t = 0; t < 8; ++t) {
        int c = t * 16 + l15;
        float b = bo[c];
#pragma unroll
        for (int r = 0; r < 4; ++r) {
            int row = rowA + quad * 4 + r;
            out[(size_t)row * DC + c] = acc[t][r] + b;
        }
    }
}

// ---------------- MFMA attention: QBLK=16, high occupancy -------------------
// block = 512 thr = 8 waves = 8 heads; grid (64 qt, 16 bt) = 1024 blocks ->
// 3-4 blocks/CU (launch_bounds(512,6) caps VGPR ~84, no spill risk).
// Per wave (1 head, 16 q-rows), per 32-key tile it:
//   S^T = K·Q^T as 2x mfma_16x16x16 (k=d=16 exact): D[key=g16+quad*4+r][q=l15]
//   P = exp2(S^T)·adj; adj tile (16x32 f32, 2 KB) staged block-wide, XOR-
//     swizzled, double-buffered; denominator accumulated in f32 (no ones-MFMA)
//   P -> wave-private LDS as ONE b128 (key-permuted cols quad*8+g*4+r),
//     double-buffered; PV of tile it-1 reads one b128 (cols quad*8..+7) and
//     one mfma_16x16x32 with the pre-permuted V frag.
// Ps row stride = 64 shorts = 128 B (power of 2!) so the XOR swizzle
// ((l15&7)<<4) is a bijection within the row — the round-3 stride-80 version
// aliased across rows (two lanes hit byte 144) and corrupted P.
// K loaded at top of iter (L2/L3-hot), V late-loaded (tile it-1), adj
// prefetched 1 tile in registers across the lgkm-only barrier.
__global__ __launch_bounds__(512, 6)
void attn_kernel(const short* __restrict__ qh, const short* __restrict__ kh,
                 const short* __restrict__ vt, const float* __restrict__ adj,
                 short* __restrict__ cb)
{
    __shared__ float As[2][16 * 32];     // adj tile dbuf, 4 KB, XOR-swizzled
    __shared__ short Ps[8][2][16 * 64];  // wave-private P dbuf, 32 KB, swizzled

    const int tid  = threadIdx.x;
    const int wave = tid >> 6;           // = head h
    const int lane = tid & 63;
    const int l15  = lane & 15;
    const int quad = lane >> 4;
    const int bt   = blockIdx.y;
    const int qt0  = blockIdx.x * 16;
    const int h    = wave;

    const size_t xb = (size_t)bt * NC * DC;
    const size_t hb = ((size_t)bt * HC + h) * NC;    // head-packed row base

    // K A-frag pointer: A[m=key=l15 (in group)][k=d=quad*4+j]
    const short* kp2 = kh + (hb + l15) * HDC + quad * 4;
    // V B-frag pointer (pre-permuted): one b128 per tile at cols quad*8
    const short* vp = vt + ((size_t)bt * DC + h * HDC + l15) * NC;
    // Q B-frag: B[k=d=quad*4+j][n=q=l15]
    const short4v Bq = *(const short4v*)&qh[(hb + qt0 + l15) * HDC + quad * 4];

    // adj staging: 512 thr x 1 dword covers the 16x32 tile, coalesced rows
    const int arow = tid >> 5;           // 0..15
    const int acol = tid & 31;
    const float* aptr = adj + (size_t)bt * NC * NC + (size_t)(qt0 + arow) * NC + acol;
    const unsigned awb = (unsigned)((arow * 128 + acol * 4) ^ ((arow & 7) << 4));

    // As read offsets (float4 per group g): row l15, cols g*16+quad*4
    const unsigned arb0 = (unsigned)((l15 * 128 + quad * 16) ^ ((l15 & 7) << 4));
    const unsigned arb1 = arb0 ^ 64;     // +64B = g=1 (bit 6 untouched: base<64)
    // Ps offset (b128, same lane writes and reads): row l15 (128 B), col 16*quad
    const unsigned pwb = (unsigned)((l15 * 128 + quad * 16) ^ ((l15 & 7) << 4));

    const f32x4 z4 = (f32x4){0.f, 0.f, 0.f, 0.f};
    f32x4 Cc = z4;
    float wsum = 0.f;

    char* AsCur = (char*)&As[0][0];
    char* AsNxt = (char*)&As[1][0];
    char* Pa = (char*)&Ps[wave][0][0];   // write target
    char* Pb = (char*)&Ps[wave][1][0];   // read target (prev tile)

    float ar = aptr[0];                  // adj tile 0

    // P = exp2(S^T)*adj -> bf16, key-permuted, ONE b128 to Pa
#define EXPBLK(ASB, PDST)                                                     \
    do {                                                                      \
        float4 a40 = *(const float4*)((ASB) + arb0);                          \
        float4 a41 = *(const float4*)((ASB) + arb1);                          \
        float p0 = EXP2F(S0[0]) * a40.x;                                      \
        float p1 = EXP2F(S0[1]) * a40.y;                                      \
        float p2 = EXP2F(S0[2]) * a40.z;                                      \
        float p3 = EXP2F(S0[3]) * a40.w;                                      \
        float p4 = EXP2F(S1[0]) * a41.x;                                      \
        float p5 = EXP2F(S1[1]) * a41.y;                                      \
        float p6 = EXP2F(S1[2]) * a41.z;                                      \
        float p7 = EXP2F(S1[3]) * a41.w;                                      \
        wsum += ((p0 + p1) + (p2 + p3)) + ((p4 + p5) + (p6 + p7));            \
        PK8 pk;                                                               \
        pk.h2[0] = __float22bfloat162_rn(make_float2(p0, p1));                \
        pk.h2[1] = __float22bfloat162_rn(make_float2(p2, p3));                \
        pk.h2[2] = __float22bfloat162_rn(make_float2(p4, p5));                \
        pk.h2[3] = __float22bfloat162_rn(make_float2(p6, p7));                \
        *(bf16x8*)((PDST) + pwb) = pk.v;                                      \
    } while (0)

    // ---- prologue: tile 0 (QK + exp only; PV lags by one tile) ----
    {
        *(float*)(AsCur + awb) = ar;
        ar = aptr[32];                   // prefetch adj tile 1
        LDS_BARRIER();
        short4v Ak0 = *(const short4v*)&kp2[0];
        short4v Ak1 = *(const short4v*)&kp2[16 * HDC];
        f32x4 S0 = qkmfma(Ak0, Bq, z4);
        f32x4 S1 = qkmfma(Ak1, Bq, z4);
        EXPBLK(AsCur, Pa);
        { char* t = Pa; Pa = Pb; Pb = t; }          // tile0 now readable in Pb
        { char* t = AsCur; AsCur = AsNxt; AsNxt = t; }
    }

#pragma unroll 2
    for (int it = 1; it < 32; ++it) {
        const int jt = it * 32;

        *(float*)(AsCur + awb) = ar;                 // stage adj tile it
        ar = aptr[(jt + 32) & (NC - 1)];             // prefetch (wrap: dead)
        LDS_BARRIER();

        short4v Ak0 = *(const short4v*)&kp2[jt * HDC];
        short4v Ak1 = *(const short4v*)&kp2[(jt + 16) * HDC];
        bf16x8  Bv  = *(const bf16x8*)&vp[jt - 32 + quad * 8];   // V(it-1)
        bf16x8  Ap  = *(const bf16x8*)(Pb + pwb);                // P(it-1)

        f32x4 S0 = qkmfma(Ak0, Bq, z4);
        f32x4 S1 = qkmfma(Ak1, Bq, z4);
        EXPBLK(AsCur, Pa);
        __builtin_amdgcn_wave_barrier();

        __builtin_amdgcn_s_setprio(1);
        Cc = __builtin_amdgcn_mfma_f32_16x16x32_bf16(Ap, Bv, Cc, 0, 0, 0);
        __builtin_amdgcn_s_setprio(0);

        { char* t = Pa; Pa = Pb; Pb = t; }
        { char* t = AsCur; AsCur = AsNxt; AsNxt = t; }
    }

    // ---- epilogue: PV of the last tile ----
    {
        bf16x8 Bv = *(const bf16x8*)&vp[992 + quad * 8];
        bf16x8 Ap = *(const bf16x8*)(Pb + pwb);
        Cc = __builtin_amdgcn_mfma_f32_16x16x32_bf16(Ap, Bv, Cc, 0, 0, 0);
    }

    // denominator: reduce wsum over the 4 quads (lanes l15, +16, +32, +48)
    wsum += __shfl_xor(wsum, 16);
    wsum += __shfl_xor(wsum, 32);

    // epilogue: ctx[q][d] = Cc/w, rows q = quad*4+r, col d = l15
#pragma unroll
    for (int r = 0; r < 4; ++r) {
        float den = __shfl(wsum, quad * 4 + r);
        float rcp = den > 0.f ? 1.f / den : 0.f;
        int row = qt0 + quad * 4 + r;
        cb[xb + (size_t)row * DC + h * HDC + l15] = f2bf(Cc[r] * rcp);
    }
#undef EXPBLK
}

extern "C" void kernel_launch(void* const* d_in, const int* in_sizes, int n_in,
                              void* d_out, int out_size, void* d_ws, size_t ws_size,
                              hipStream_t stream)
{
    const float* x   = (const float*)d_in[0];
    const float* adj = (const float*)d_in[1];
    const float* Wq  = (const float*)d_in[2];
    const float* bq  = (const float*)d_in[3];
    const float* Wk  = (const float*)d_in[4];
    const float* bk  = (const float*)d_in[5];
    const float* Wv  = (const float*)d_in[6];
    const float* bv  = (const float*)d_in[7];
    const float* Wo  = (const float*)d_in[8];
    const float* bo  = (const float*)d_in[9];
    float* out = (float*)d_out;

    const size_t tok = (size_t)BTC * NC * DC;   // 2,097,152
    short* xbf  = (short*)d_ws;
    short* Wbf  = xbf  + tok;        // 4 * 16384
    short* qbuf = Wbf  + 65536;      // head-packed [bt][h][n][16]
    short* kbuf = qbuf + tok;        // head-packed [bt][h][n][16]
    short* vt   = kbuf + tok;        // transposed + key-permuted [bt][d][n']
    short* cbuf = vt   + tok;

    prep_kernel<<<2112, 256, 0, stream>>>(x, Wq, Wk, Wv, Wo, xbf, Wbf);

    dim3 pgrid(256, 3);
    proj_qkv<<<pgrid, 256, 0, stream>>>(xbf, Wbf, bq, bk, bv, qbuf, kbuf, vt);

    dim3 agrid(64, 16);
    attn_kernel<<<agrid, 512, 0, stream>>>(qbuf, kbuf, vt, adj, cbuf);

    proj_out<<<256, 256, 0, stream>>>(cbuf, Wbf + 3 * 16384, bo, out);
}

// Round 5
// 188.659 us; speedup vs baseline: 1.0870x; 1.0870x over previous
//
#include <hip/hip_runtime.h>
#include <hip/hip_bf16.h>

#define BTC 16
#define NC 1024
#define DC 128
#define HC 8
#define HDC 16

typedef __attribute__((ext_vector_type(8))) short bf16x8;   // 8 bf16 = 4 VGPR
typedef __attribute__((ext_vector_type(4))) float f32x4;    // MFMA C/D frag 16x16
typedef __attribute__((ext_vector_type(16))) float f32x16;  // MFMA C/D frag 32x32
typedef __attribute__((ext_vector_type(4))) short short4v;  // 4 bf16 = 2 VGPR

#if __has_builtin(__builtin_amdgcn_exp2f)
#define EXP2F(x) __builtin_amdgcn_exp2f(x)
#else
#define EXP2F(x) exp2f(x)
#endif

// q scale: 0.25 (1/sqrt(HD)) * log2(e)  -> attention uses exp2 directly
#define QSCALE 0.36067376022224085f

union PK2  { short4v s4; __hip_bfloat162 h2[2]; };
union PK2u { unsigned u[2]; __hip_bfloat162 h2[2]; };
union PK8  { bf16x8 v; short s[8]; __hip_bfloat162 h2[4]; };
union AFRAG { unsigned u[4]; bf16x8 v; };

static __device__ inline short f2bf(float f) {               // RNE f32->bf16
    unsigned u = __builtin_bit_cast(unsigned, f);
    u += 0x7fffu + ((u >> 16) & 1u);
    return (short)(u >> 16);
}

// v_permlane32_swap_b32 a, b:  a.upper <-> b.lower
// after: a[i<32]=a, a[i+32]=b[i], b[i]=old a[i+32], b[i+32]=b
static __device__ inline void pl32swap(unsigned &a, unsigned &b) {
    asm volatile("v_permlane32_swap_b32 %0, %1" : "+v"(a), "+v"(b));
}

// raw workgroup barrier: LDS-visibility only (lgkmcnt), keeps global register
// prefetches (vmcnt) in flight across the barrier (unlike __syncthreads).
#define LDS_BARRIER()                                              \
    do {                                                           \
        asm volatile("s_waitcnt lgkmcnt(0)" ::: "memory");         \
        __builtin_amdgcn_s_barrier();                              \
        asm volatile("" ::: "memory");                             \
    } while (0)

// ---------------- prep: fp32 -> bf16 for x + weights, and vt2 pad rows ------
// blocks 0..2111: convert x and the 4 W matrices.
// blocks 2112..3135: fill vt2 rows 16..31 per (bt,h): row16 = 1.0 (row-sum
// column for the PV MFMA), rows 17..31 = 0 (outputs ignored but finite).
__global__ __launch_bounds__(256)
void prep_kernel(const float* __restrict__ x,
                 const float* __restrict__ Wq, const float* __restrict__ Wk,
                 const float* __restrict__ Wv, const float* __restrict__ Wo,
                 short* __restrict__ xbf, short* __restrict__ Wbf,
                 short* __restrict__ vt2)
{
    if (blockIdx.x >= 2112) {
        int idx8 = (blockIdx.x - 2112) * 256 + threadIdx.x;   // 0..262143
        int g  = idx8 >> 11;          // (bt*8+h) 0..127
        int r  = (idx8 >> 7) & 15;    // 0..15 -> rows 16..31
        int c8 = idx8 & 127;
        short val = (r == 0) ? (short)0x3F80 : (short)0;
        PK8 u;
#pragma unroll
        for (int j = 0; j < 8; ++j) u.s[j] = val;
        *(bf16x8*)&vt2[((size_t)g * 32 + 16 + r) * NC + c8 * 8] = u.v;
        return;
    }
    int gid  = blockIdx.x * 256 + threadIdx.x;
    int base = gid * 4;
    const float* src;
    short* dst;
    if (base < 2097152) {                      // x: 16*1024*128
        src = x + base; dst = xbf + base;
    } else {
        int idx = base - 2097152;              // 0..65535 over 4 W's
        int w   = idx >> 14;
        int off = idx & 16383;
        src = ((w == 0) ? Wq : (w == 1) ? Wk : (w == 2) ? Wv : Wo) + off;
        dst = Wbf + w * 16384 + off;
    }
    float4 v = *(const float4*)src;
    PK2 pk;
    pk.h2[0] = __float22bfloat162_rn(make_float2(v.x, v.y));
    pk.h2[1] = __float22bfloat162_rn(make_float2(v.z, v.w));
    *(short4v*)dst = pk.s4;
}

// ---------------- MFMA projection, C = X @ W^T + b --------------------------
// block = 256 thr (4 waves), wave = 16 rows x 128 cols, K-loop 4x32.
// y = 0: q (scale QSCALE), 1: k — BOTH stored head-packed [bt][h][n][16].
// y = 2: v stored transposed vt2[(bt*8+h)*32 + d][n] (32 d-rows per head;
//        rows 16..31 are the ones/zeros pad written by prep).
__global__ __launch_bounds__(256)
void proj_qkv(const short* __restrict__ xbf, const short* __restrict__ Wbf,
              const float* __restrict__ bq, const float* __restrict__ bk,
              const float* __restrict__ bv,
              short* __restrict__ qo, short* __restrict__ ko, short* __restrict__ vto)
{
    __shared__ short T[128 * 72];        // 18.4 KB transpose tile (y==2 only)

    const int y = blockIdx.y;
    const short* W = Wbf + y * 16384;
    const float* bias = (y == 0) ? bq : (y == 1) ? bk : bv;
    const float scale = (y == 0) ? QSCALE : 1.0f;

    const int tid  = threadIdx.x;
    const int wave = tid >> 6;
    const int lane = tid & 63;
    const int l15  = lane & 15;
    const int quad = lane >> 4;
    const int rowA = blockIdx.x * 64 + wave * 16;

    f32x4 acc[8];
#pragma unroll
    for (int t = 0; t < 8; ++t) acc[t] = (f32x4){0.f, 0.f, 0.f, 0.f};

#pragma unroll
    for (int kk = 0; kk < DC; kk += 32) {
        bf16x8 Af = *(const bf16x8*)&xbf[(size_t)(rowA + l15) * DC + kk + quad * 8];
#pragma unroll
        for (int t = 0; t < 8; ++t) {
            bf16x8 Bf = *(const bf16x8*)&W[(t * 16 + l15) * DC + kk + quad * 8];
            acc[t] = __builtin_amdgcn_mfma_f32_16x16x32_bf16(Af, Bf, acc[t], 0, 0, 0);
        }
    }

    if (y == 2) {
        // transpose through LDS: T[c][local_row], row stride 72 shorts
#pragma unroll
        for (int t = 0; t < 8; ++t) {
            int c = t * 16 + l15;
            float b = bias[c];
            PK2 pk;
            pk.h2[0] = __float22bfloat162_rn(make_float2(acc[t][0] + b, acc[t][1] + b));
            pk.h2[1] = __float22bfloat162_rn(make_float2(acc[t][2] + b, acc[t][3] + b));
            *(short4v*)&T[c * 72 + wave * 16 + quad * 4] = pk.s4;
        }
        __syncthreads();                  // y uniform per block: no divergence
        const int bt = blockIdx.x >> 4;
        const int n0 = (blockIdx.x * 64) & 1023;
        const int chunk = tid & 7;        // 8 chunks x 16 B = one 128-B d-row
        const int dr    = tid >> 3;       // 0..31
#pragma unroll
        for (int rep = 0; rep < 4; ++rep) {
            int d = rep * 32 + dr;        // 0..127 = h*16 + dd
            bf16x8 u = *(const bf16x8*)&T[d * 72 + chunk * 8];
            size_t row = (size_t)(bt * HC + (d >> 4)) * 32 + (d & 15);
            *(bf16x8*)&vto[row * NC + n0 + chunk * 8] = u;
        }
    } else {
        short* dst = (y == 0) ? qo : ko;
#pragma unroll
        for (int t = 0; t < 8; ++t) {
            int c  = t * 16 + l15;
            int hh = c >> 4, dd = c & 15;
            float b = bias[c];
#pragma unroll
            for (int r = 0; r < 4; ++r) {
                int row = rowA + quad * 4 + r;       // = bt*1024 + n
                int btq = row >> 10, n = row & 1023;
                float val = (acc[t][r] + b) * scale;
                dst[(((size_t)btq * HC + hh) * NC + n) * HDC + dd] = f2bf(val);
            }
        }
    }
}

// out-projection: bf16 ctx in, fp32 out
__global__ __launch_bounds__(256)
void proj_out(const short* __restrict__ cbf, const short* __restrict__ Wobf,
              const float* __restrict__ bo, float* __restrict__ out)
{
    const int tid  = threadIdx.x;
    const int wave = tid >> 6;
    const int lane = tid & 63;
    const int l15  = lane & 15;
    const int quad = lane >> 4;
    const int rowA = blockIdx.x * 64 + wave * 16;

    f32x4 acc[8];
#pragma unroll
    for (int t = 0; t < 8; ++t) acc[t] = (f32x4){0.f, 0.f, 0.f, 0.f};

#pragma unroll
    for (int kk = 0; kk < DC; kk += 32) {
        bf16x8 Af = *(const bf16x8*)&cbf[(size_t)(rowA + l15) * DC + kk + quad * 8];
#pragma unroll
        for (int t = 0; t < 8; ++t) {
            bf16x8 Bf = *(const bf16x8*)&Wobf[(t * 16 + l15) * DC + kk + quad * 8];
            acc[t] = __builtin_amdgcn_mfma_f32_16x16x32_bf16(Af, Bf, acc[t], 0, 0, 0);
        }
    }

#pragma unroll
    for (int t = 0; t < 8; ++t) {
        int c = t * 16 + l15;
        float b = bo[c];
#pragma unroll
        for (int r = 0; r < 4; ++r) {
            int row = rowA + quad * 4 + r;
            out[(size_t)row * DC + c] = acc[t][r] + b;
        }
    }
}

// ---------------- MFMA attention: in-register P via permlane32_swap ---------
// block = 256 thr = 4 waves = 4 heads; grid (32 qt, 16 bt, 2 hz) = 1024 blocks.
// Per wave (1 head, 32 q-rows), per 32-key tile:
//   S^T = K·Q in ONE mfma_32x32x16 (k=d=16): D[key=(reg&3)+8(reg>>2)+4hi][q=l31]
//   P = exp2(S^T)·adj (adj from block-staged XOR-swizzled LDS, 64-key chunks,
//     dbuf, ONE lgkm-only barrier per chunk)
//   P -> bf16 via cvt_pk; lanes (i, i+32) hold complementary key-halves of the
//     SAME q-row, so 2x v_permlane32_swap_b32 builds each PV A-frag
//     A[m=q=l31][k=hi*8+j] IN REGISTERS — no P LDS bounce, no wave_barrier.
//   ctx += P·V as 2x mfma_32x32x16 with V2 padded to 32 n-rows per head:
//     row16 = 1.0 -> D[q][16] accumulates the row-sum for free.
// K/V/adj prefetched one chunk ahead in registers across the barrier.
__global__ __launch_bounds__(256, 4)
void attn_kernel(const short* __restrict__ qh, const short* __restrict__ kh,
                 const short* __restrict__ vt, const float* __restrict__ adj,
                 short* __restrict__ cb)
{
    __shared__ float As[2][32 * 64];     // adj chunk dbuf, 16 KB, XOR-swizzled

    const int tid  = threadIdx.x;
    const int wave = tid >> 6;
    const int lane = tid & 63;
    const int l31  = lane & 31;
    const int hi   = lane >> 5;
    const int bt   = blockIdx.y;
    const int qt0  = blockIdx.x * 32;
    const int h    = blockIdx.z * 4 + wave;

    const size_t xb = (size_t)bt * NC * DC;
    const size_t hb = ((size_t)bt * HC + h) * NC;    // head-packed row base

    // K A-frag: A[m=key=l31][k=d=hi*8+j] -> coalesced 1KB/wave per tile
    const short* kpl = kh + (hb + l31) * HDC + hi * 8;
    // V B-frag: B[k=key=hi*8+j][n=d-row=l31] from vt2[(bt*8+h)*32+l31][key]
    const short* vpl = vt + ((size_t)(bt * HC + h) * 32 + l31) * NC + hi * 8;
    // Q B-frag: B[k=d=hi*8+j][n=q=l31] (QSCALE folded at proj)
    const bf16x8 Bq = *(const bf16x8*)&qh[(hb + qt0 + l31) * HDC + hi * 8];

    // adj staging: 256 thr x 2 float4 cover the 32x64 f32 chunk, coalesced
    const int arow = tid >> 4;            // 0..15 (second store: +16)
    const int acol = tid & 15;            // float4 index in row
    const float* apA = adj + (size_t)bt * NC * NC + (size_t)(qt0 + arow) * NC + acol * 4;
    const float* apB = apA + 16 * NC;

    const unsigned swz   = (unsigned)((l31 & 7) << 4);
    const unsigned woff0 = (unsigned)((arow * 256 + acol * 16) ^ ((arow & 7) << 4));
    const unsigned woff1 = (unsigned)(((arow + 16) * 256 + acol * 16) ^ ((arow & 7) << 4));

    f32x16 Z16, Cc;
#pragma unroll
    for (int i = 0; i < 16; ++i) { Z16[i] = 0.f; Cc[i] = 0.f; }

    // P-build + PV for one 32-key tile. S reg -> key=(reg&3)+8*(reg>>2)+4*hi,
    // adj float4 per reg-group gg at col byte TOFF+gg*32+hi*16 (swizzled).
#define PKPAIR(ca, cbb, s0, s1, s2, s3, a4)                                   \
    {                                                                         \
        float p0 = EXP2F(s0) * a4.x;                                          \
        float p1 = EXP2F(s1) * a4.y;                                          \
        float p2 = EXP2F(s2) * a4.z;                                          \
        float p3 = EXP2F(s3) * a4.w;                                          \
        PK2u pk;                                                              \
        pk.h2[0] = __float22bfloat162_rn(make_float2(p0, p1));                \
        pk.h2[1] = __float22bfloat162_rn(make_float2(p2, p3));                \
        ca = pk.u[0]; cbb = pk.u[1];                                          \
    }
#define PTILE(S, TOFF, BVA, BVB)                                              \
    do {                                                                      \
        unsigned c0, c1, c2, c3, c4, c5, c6, c7;                              \
        float4 a4;                                                            \
        a4 = *(const float4*)(AsR + (((TOFF) + 0 * 32 + hi * 16) ^ swz));     \
        PKPAIR(c0, c1, S[0], S[1], S[2], S[3], a4);                           \
        a4 = *(const float4*)(AsR + (((TOFF) + 1 * 32 + hi * 16) ^ swz));     \
        PKPAIR(c2, c3, S[4], S[5], S[6], S[7], a4);                           \
        a4 = *(const float4*)(AsR + (((TOFF) + 2 * 32 + hi * 16) ^ swz));     \
        PKPAIR(c4, c5, S[8], S[9], S[10], S[11], a4);                         \
        a4 = *(const float4*)(AsR + (((TOFF) + 3 * 32 + hi * 16) ^ swz));     \
        PKPAIR(c6, c7, S[12], S[13], S[14], S[15], a4);                       \
        pl32swap(c0, c2); pl32swap(c1, c3);                                   \
        pl32swap(c4, c6); pl32swap(c5, c7);                                   \
        AFRAG f1, f2;                                                         \
        f1.u[0] = c0; f1.u[1] = c1; f1.u[2] = c2; f1.u[3] = c3;               \
        f2.u[0] = c4; f2.u[1] = c5; f2.u[2] = c6; f2.u[3] = c7;               \
        __builtin_amdgcn_s_setprio(1);                                        \
        Cc = __builtin_amdgcn_mfma_f32_32x32x16_bf16(f1.v, BVA, Cc, 0, 0, 0); \
        Cc = __builtin_amdgcn_mfma_f32_32x32x16_bf16(f2.v, BVB, Cc, 0, 0, 0); \
        __builtin_amdgcn_s_setprio(0);                                        \
    } while (0)

    // prologue prefetch: chunk 0
    float4 arA  = *(const float4*)apA;
    float4 arB  = *(const float4*)apB;
    bf16x8 Ak0  = *(const bf16x8*)&kpl[0];
    bf16x8 Bv00 = *(const bf16x8*)&vpl[0];
    bf16x8 Bv01 = *(const bf16x8*)&vpl[16];

    int cbuf = 0;
    for (int c = 0; c < 16; ++c) {
        const int jt = c * 64;
        char* AsW = (char*)&As[cbuf][0];
        *(float4*)(AsW + woff0) = arA;               // waits only adj vmcnt
        *(float4*)(AsW + woff1) = arB;

        // current chunk, tile 1 operands (consumed ~400cy later)
        bf16x8 Ak1  = *(const bf16x8*)&kpl[(jt + 32) * HDC];
        bf16x8 Bv10 = *(const bf16x8*)&vpl[jt + 32];
        bf16x8 Bv11 = *(const bf16x8*)&vpl[jt + 48];

        // next chunk prefetch (rides across the barrier; wrap: dead loads)
        const int nj = (jt + 64) & (NC - 1);
        arA = *(const float4*)(apA + nj);
        arB = *(const float4*)(apB + nj);
        bf16x8 Ak0n  = *(const bf16x8*)&kpl[nj * HDC];
        bf16x8 Bv00n = *(const bf16x8*)&vpl[nj];
        bf16x8 Bv01n = *(const bf16x8*)&vpl[nj + 16];

        LDS_BARRIER();
        const char* AsR = (const char*)&As[cbuf][0] + l31 * 256;

        f32x16 S0 = __builtin_amdgcn_mfma_f32_32x32x16_bf16(Ak0, Bq, Z16, 0, 0, 0);
        PTILE(S0, 0, Bv00, Bv01);
        f32x16 S1 = __builtin_amdgcn_mfma_f32_32x32x16_bf16(Ak1, Bq, Z16, 0, 0, 0);
        PTILE(S1, 128, Bv10, Bv11);

        Ak0 = Ak0n; Bv00 = Bv00n; Bv01 = Bv01n;
        cbuf ^= 1;
    }
#undef PTILE
#undef PKPAIR

    // epilogue: D[q=(reg&3)+8(reg>>2)+4hi][n=l31]; n=16 column = row-sum
#pragma unroll
    for (int reg = 0; reg < 16; ++reg) {
        float w = __shfl(Cc[reg], 16 + (hi << 5), 64);
        float rcp = w > 0.f ? 1.f / w : 0.f;
        int q = qt0 + (reg & 3) + 8 * (reg >> 2) + 4 * hi;
        if (l31 < 16)
            cb[xb + (size_t)q * DC + h * HDC + l31] = f2bf(Cc[reg] * rcp);
    }
}

extern "C" void kernel_launch(void* const* d_in, const int* in_sizes, int n_in,
                              void* d_out, int out_size, void* d_ws, size_t ws_size,
                              hipStream_t stream)
{
    const float* x   = (const float*)d_in[0];
    const float* adj = (const float*)d_in[1];
    const float* Wq  = (const float*)d_in[2];
    const float* bq  = (const float*)d_in[3];
    const float* Wk  = (const float*)d_in[4];
    const float* bk  = (const float*)d_in[5];
    const float* Wv  = (const float*)d_in[6];
    const float* bv  = (const float*)d_in[7];
    const float* Wo  = (const float*)d_in[8];
    const float* bo  = (const float*)d_in[9];
    float* out = (float*)d_out;

    const size_t tok = (size_t)BTC * NC * DC;   // 2,097,152
    short* xbf  = (short*)d_ws;
    short* Wbf  = xbf  + tok;        // 4 * 16384
    short* qbuf = Wbf  + 65536;      // head-packed [bt][h][n][16]
    short* kbuf = qbuf + tok;        // head-packed [bt][h][n][16]
    short* vt2  = kbuf + tok;        // [bt][h][32 d-rows][n], rows 16+ = pad
    short* cbuf = vt2  + (size_t)BTC * HC * 32 * NC;   // 4,194,304

    prep_kernel<<<3136, 256, 0, stream>>>(x, Wq, Wk, Wv, Wo, xbf, Wbf, vt2);

    dim3 pgrid(256, 3);
    proj_qkv<<<pgrid, 256, 0, stream>>>(xbf, Wbf, bq, bk, bv, qbuf, kbuf, vt2);

    dim3 agrid(32, 16, 2);
    attn_kernel<<<agrid, 256, 0, stream>>>(qbuf, kbuf, vt2, adj, cbuf);

    proj_out<<<256, 256, 0, stream>>>(cbuf, Wbf + 3 * 16384, bo, out);
}

// Round 6
// 174.645 us; speedup vs baseline: 1.1742x; 1.0802x over previous
//
#include <hip/hip_runtime.h>
#include <hip/hip_bf16.h>

#define BTC 16
#define NC 1024
#define DC 128
#define HC 8
#define HDC 16

typedef __attribute__((ext_vector_type(8))) short bf16x8;   // 8 bf16 = 4 VGPR
typedef __attribute__((ext_vector_type(4))) float f32x4;    // MFMA C/D frag 16x16
typedef __attribute__((ext_vector_type(16))) float f32x16;  // MFMA C/D frag 32x32
typedef __attribute__((ext_vector_type(4))) short short4v;  // 4 bf16 = 2 VGPR

#if __has_builtin(__builtin_amdgcn_exp2f)
#define EXP2F(x) __builtin_amdgcn_exp2f(x)
#else
#define EXP2F(x) exp2f(x)
#endif

// q scale: 0.25 (1/sqrt(HD)) * log2(e)  -> attention uses exp2 directly
#define QSCALE 0.36067376022224085f

union PK2 { short4v s4; __hip_bfloat162 h2[2]; };
union PK8 { bf16x8 v; short s[8]; __hip_bfloat162 h2[4]; };

static __device__ inline short f2bf(float f) {               // RNE f32->bf16
    unsigned u = __builtin_bit_cast(unsigned, f);
    u += 0x7fffu + ((u >> 16) & 1u);
    return (short)(u >> 16);
}

// raw workgroup barrier: LDS-visibility only (lgkmcnt), keeps global register
// prefetches (vmcnt) in flight across the barrier (unlike __syncthreads).
#define LDS_BARRIER()                                              \
    do {                                                           \
        asm volatile("s_waitcnt lgkmcnt(0)" ::: "memory");         \
        __builtin_amdgcn_s_barrier();                              \
        asm volatile("" ::: "memory");                             \
    } while (0)

// ---------------- prep: fp32 -> bf16 for x and the 4 weight matrices --------
__global__ __launch_bounds__(256)
void prep_kernel(const float* __restrict__ x,
                 const float* __restrict__ Wq, const float* __restrict__ Wk,
                 const float* __restrict__ Wv, const float* __restrict__ Wo,
                 short* __restrict__ xbf, short* __restrict__ Wbf)
{
    int gid  = blockIdx.x * 256 + threadIdx.x;
    int base = gid * 4;
    const float* src;
    short* dst;
    if (base < 2097152) {                      // x: 16*1024*128
        src = x + base; dst = xbf + base;
    } else {
        int idx = base - 2097152;              // 0..65535 over 4 W's
        int w   = idx >> 14;
        int off = idx & 16383;
        src = ((w == 0) ? Wq : (w == 1) ? Wk : (w == 2) ? Wv : Wo) + off;
        dst = Wbf + w * 16384 + off;
    }
    float4 v = *(const float4*)src;
    PK2 pk;
    pk.h2[0] = __float22bfloat162_rn(make_float2(v.x, v.y));
    pk.h2[1] = __float22bfloat162_rn(make_float2(v.z, v.w));
    *(short4v*)dst = pk.s4;
}

// ---------------- MFMA projection, C = X @ W^T + b --------------------------
// block = 256 thr (4 waves), wave = 16 rows x 128 cols, K-loop 4x32.
// y = 0: q (scale QSCALE), 1: k — BOTH stored head-packed [bt][h][n][16] so
// the attention kernel's per-tile K load is one fully-coalesced 1KB wave load.
// y = 2: v stored transposed vt[bt][d][n] via LDS transpose -> 16B stores.
__global__ __launch_bounds__(256)
void proj_qkv(const short* __restrict__ xbf, const short* __restrict__ Wbf,
              const float* __restrict__ bq, const float* __restrict__ bk,
              const float* __restrict__ bv,
              short* __restrict__ qo, short* __restrict__ ko, short* __restrict__ vto)
{
    __shared__ short T[128 * 72];        // 18.4 KB transpose tile (y==2 only)

    const int y = blockIdx.y;
    const short* W = Wbf + y * 16384;
    const float* bias = (y == 0) ? bq : (y == 1) ? bk : bv;
    const float scale = (y == 0) ? QSCALE : 1.0f;

    const int tid  = threadIdx.x;
    const int wave = tid >> 6;
    const int lane = tid & 63;
    const int l15  = lane & 15;
    const int quad = lane >> 4;
    const int rowA = blockIdx.x * 64 + wave * 16;

    f32x4 acc[8];
#pragma unroll
    for (int t = 0; t < 8; ++t) acc[t] = (f32x4){0.f, 0.f, 0.f, 0.f};

#pragma unroll
    for (int kk = 0; kk < DC; kk += 32) {
        bf16x8 Af = *(const bf16x8*)&xbf[(size_t)(rowA + l15) * DC + kk + quad * 8];
#pragma unroll
        for (int t = 0; t < 8; ++t) {
            bf16x8 Bf = *(const bf16x8*)&W[(t * 16 + l15) * DC + kk + quad * 8];
            acc[t] = __builtin_amdgcn_mfma_f32_16x16x32_bf16(Af, Bf, acc[t], 0, 0, 0);
        }
    }

    if (y == 2) {
        // transpose through LDS: T[c][local_row], row stride 72 shorts (144 B,
        // 16-B aligned for b128 reads; bank-minimal b64 writes)
#pragma unroll
        for (int t = 0; t < 8; ++t) {
            int c = t * 16 + l15;
            float b = bias[c];
            PK2 pk;
            pk.h2[0] = __float22bfloat162_rn(make_float2(acc[t][0] + b, acc[t][1] + b));
            pk.h2[1] = __float22bfloat162_rn(make_float2(acc[t][2] + b, acc[t][3] + b));
            *(short4v*)&T[c * 72 + wave * 16 + quad * 4] = pk.s4;
        }
        __syncthreads();                  // y uniform per block: no divergence
        const int bt = blockIdx.x >> 4;
        const int n0 = (blockIdx.x * 64) & 1023;
        const int chunk = tid & 7;        // 8 chunks x 16 B = one 128-B d-row
        const int dr    = tid >> 3;       // 0..31
#pragma unroll
        for (int rep = 0; rep < 4; ++rep) {
            int d = rep * 32 + dr;
            bf16x8 u = *(const bf16x8*)&T[d * 72 + chunk * 8];
            *(bf16x8*)&vto[((size_t)bt * DC + d) * NC + n0 + chunk * 8] = u;
        }
    } else {
        short* dst = (y == 0) ? qo : ko;
#pragma unroll
        for (int t = 0; t < 8; ++t) {
            int c  = t * 16 + l15;
            int hh = c >> 4, dd = c & 15;
            float b = bias[c];
#pragma unroll
            for (int r = 0; r < 4; ++r) {
                int row = rowA + quad * 4 + r;       // = bt*1024 + n
                int btq = row >> 10, n = row & 1023;
                float val = (acc[t][r] + b) * scale;
                dst[(((size_t)btq * HC + hh) * NC + n) * HDC + dd] = f2bf(val);
            }
        }
    }
}

// out-projection: bf16 ctx in, fp32 out
__global__ __launch_bounds__(256)
void proj_out(const short* __restrict__ cbf, const short* __restrict__ Wobf,
              const float* __restrict__ bo, float* __restrict__ out)
{
    const int tid  = threadIdx.x;
    const int wave = tid >> 6;
    const int lane = tid & 63;
    const int l15  = lane & 15;
    const int quad = lane >> 4;
    const int rowA = blockIdx.x * 64 + wave * 16;

    f32x4 acc[8];
#pragma unroll
    for (int t = 0; t < 8; ++t) acc[t] = (f32x4){0.f, 0.f, 0.f, 0.f};

#pragma unroll
    for (int kk = 0; kk < DC; kk += 32) {
        bf16x8 Af = *(const bf16x8*)&cbf[(size_t)(rowA + l15) * DC + kk + quad * 8];
#pragma unroll
        for (int t = 0; t < 8; ++t) {
            bf16x8 Bf = *(const bf16x8*)&Wobf[(t * 16 + l15) * DC + kk + quad * 8];
            acc[t] = __builtin_amdgcn_mfma_f32_16x16x32_bf16(Af, Bf, acc[t], 0, 0, 0);
        }
    }

#pragma unroll
    for (int t = 0; t < 8; ++t) {
        int c = t * 16 + l15;
        float b = bo[c];
#pragma unroll
        for (int r = 0; r < 4; ++r) {
            int row = rowA + quad * 4 + r;
            out[(size_t)row * DC + c] = acc[t][r] + b;
        }
    }
}

// ---------------- MFMA attention: round-2 dataflow, 4-wave blocks -----------
// block = 256 thr = 4 waves = 4 heads; grid (32 qt, 16 bt, 2 hz) = 1024
// blocks -> 4 independent barrier-groups/CU (vs round 2's 2). Per wave
// (1 head, 32 q-rows), per 32-key tile it:
//   S^T = K·Q in ONE mfma_32x32x16 (k=d=16): D[key=(reg&3)+8(reg>>2)+4hi][q=l31]
//   P = exp2(S^T)·adj -> bf16 -> wave-private LDS dbuf (4x b64)
//   PV of tile it-1: 2x b128 P-read + 4x mfma_16x16x32 (V frag + ones frag)
// Schedule changes vs round 2:
//   * store-early/barrier-late: adj(it+1) is written to the spare As buffer
//     at the TOP of iter it (register-prefetched one iter earlier); the single
//     LDS_BARRIER sits at the END of the iter, so its lgkm-drain has a full
//     iteration of slack and the As read for tile it+1 starts right after it.
//   * As reads hoisted (4 float4 issued back-to-back, one latency not four).
//   * PV MFMAs issue right after the QK MFMA (independent of S) so the exp
//     chain's VALU overlaps MFMA execution.
__global__ __launch_bounds__(256, 4)
void attn_kernel(const short* __restrict__ qh, const short* __restrict__ kh,
                 const short* __restrict__ vt, const float* __restrict__ adj,
                 short* __restrict__ cb)
{
    __shared__ float As[2][32 * 36];     // adj tile dbuf, 9.2 KB
    __shared__ short Ps[4][2][32 * 40];  // wave-private P dbuf, 20.5 KB

    const int tid  = threadIdx.x;
    const int wave = tid >> 6;
    const int lane = tid & 63;
    const int l31  = lane & 31;
    const int hi   = lane >> 5;
    const int l15  = lane & 15;
    const int quad = lane >> 4;
    const int bt   = blockIdx.y;
    const int qt0  = blockIdx.x * 32;
    const int h    = blockIdx.z * 4 + wave;

    const size_t xb = (size_t)bt * NC * DC;
    const size_t hb = ((size_t)bt * HC + h) * NC;    // head-packed row base

    // K A-frag: A[m=key=l31][k=d=hi*8+j]; per-tile load = kp[jt*HDC]
    const short* kp = kh + (hb + l31) * HDC + hi * 8;
    // V B-frag: B[k=key=quad*8+j][n=d=l15]; per-tile load = vp[jt + quad*8]
    const short* vp = vt + ((size_t)bt * DC + h * HDC + l15) * NC;
    // Q B-frag: B[k=d=hi*8+j][n=q=l31] (QSCALE folded at proj)
    const bf16x8 Bq = *(const bf16x8*)&qh[(hb + qt0 + l31) * HDC + hi * 8];

    // adj staging: 256 thr x 1 float4 cover the 32x32 f32 tile, coalesced rows
    const int arow = tid >> 3;           // 0..31
    const int acol = (tid & 7) * 4;      // float col 0..28
    const float* aptr = adj + (size_t)bt * NC * NC + (size_t)(qt0 + arow) * NC + acol;
    const int awoff = arow * 36 + acol;  // byte-16-aligned (144,16 both %16==0)

    PK8 ones;
#pragma unroll
    for (int j = 0; j < 8; ++j) ones.s[j] = (short)0x3F80;   // bf16 1.0

    f32x16 Z16;
#pragma unroll
    for (int i = 0; i < 16; ++i) Z16[i] = 0.f;               // hoisted zero C

    f32x4 Cc[2], Cw[2];
#pragma unroll
    for (int s = 0; s < 2; ++s) {
        Cc[s] = (f32x4){0.f, 0.f, 0.f, 0.f};
        Cw[s] = (f32x4){0.f, 0.f, 0.f, 0.f};
    }

    short* Pa = &Ps[wave][0][0];         // write target
    short* Pb = &Ps[wave][1][0];         // read target (prev tile)

    // prologue prefetch: tile 0
    float4 ar = *(const float4*)aptr;                 // adj(0)
    bf16x8 Ak = *(const bf16x8*)&kp[0];               // K(0)
    bf16x8 Bv = *(const bf16x8*)&vp[quad * 8];        // V(0)
    bf16x8 Bvp;

    // P = exp2(S^T)*adj -> bf16 -> wave-private LDS. As reads hoisted.
    // P col = t*8 + hi*4 + r for S[4t+r]; As col = t*8 + hi*4.
#define EXPTILE(ASB, PDST)                                                    \
    do {                                                                      \
        const float* asb = (ASB) + l31 * 36 + hi * 4;                         \
        float4 a0 = *(const float4*)&asb[0];                                  \
        float4 a1 = *(const float4*)&asb[8];                                  \
        float4 a2 = *(const float4*)&asb[16];                                 \
        float4 a3 = *(const float4*)&asb[24];                                 \
        short* pd = (PDST) + l31 * 40 + hi * 4;                               \
        PK2 pk;                                                               \
        pk.h2[0] = __float22bfloat162_rn(                                     \
            make_float2(EXP2F(S[0]) * a0.x, EXP2F(S[1]) * a0.y));             \
        pk.h2[1] = __float22bfloat162_rn(                                     \
            make_float2(EXP2F(S[2]) * a0.z, EXP2F(S[3]) * a0.w));             \
        *(short4v*)&pd[0] = pk.s4;                                            \
        pk.h2[0] = __float22bfloat162_rn(                                     \
            make_float2(EXP2F(S[4]) * a1.x, EXP2F(S[5]) * a1.y));             \
        pk.h2[1] = __float22bfloat162_rn(                                     \
            make_float2(EXP2F(S[6]) * a1.z, EXP2F(S[7]) * a1.w));             \
        *(short4v*)&pd[8] = pk.s4;                                            \
        pk.h2[0] = __float22bfloat162_rn(                                     \
            make_float2(EXP2F(S[8]) * a2.x, EXP2F(S[9]) * a2.y));             \
        pk.h2[1] = __float22bfloat162_rn(                                     \
            make_float2(EXP2F(S[10]) * a2.z, EXP2F(S[11]) * a2.w));           \
        *(short4v*)&pd[16] = pk.s4;                                           \
        pk.h2[0] = __float22bfloat162_rn(                                     \
            make_float2(EXP2F(S[12]) * a3.x, EXP2F(S[13]) * a3.y));           \
        pk.h2[1] = __float22bfloat162_rn(                                     \
            make_float2(EXP2F(S[14]) * a3.z, EXP2F(S[15]) * a3.w));           \
        *(short4v*)&pd[24] = pk.s4;                                           \
    } while (0)

    // stage adj(0), prefetch adj(1), make tile 0 visible
    *(float4*)((char*)&As[0][0] + 0 + awoff * 4) = ar;
    ar = *(const float4*)(aptr + 32);                 // adj(1)
    LDS_BARRIER();

    // ---- iter 0: QK + exp only (PV lags one tile) ----
    {
        *(float4*)&As[1][awoff] = ar;                 // stage adj(1) early
        ar = *(const float4*)(aptr + 64);             // prefetch adj(2)
        bf16x8 Akn = *(const bf16x8*)&kp[32 * HDC];
        bf16x8 Bvn = *(const bf16x8*)&vp[32 + quad * 8];
        f32x16 S = __builtin_amdgcn_mfma_f32_32x32x16_bf16(Ak, Bq, Z16, 0, 0, 0);
        EXPTILE(&As[0][0], Pa);
        LDS_BARRIER();                                // P(0) + As[1] visible
        { short* t = Pa; Pa = Pb; Pb = t; }
        Ak = Akn; Bvp = Bv; Bv = Bvn;
    }

#pragma unroll 2
    for (int it = 1; it < 32; ++it) {
        const int jt  = it * 32;
        const int cur = it & 1;                       // As[cur] holds adj(it)

        *(float4*)&As[cur ^ 1][awoff] = ar;           // stage adj(it+1) early
        ar = *(const float4*)(aptr + ((jt + 64) & (NC - 1)));   // adj(it+2)

        bf16x8 Akn = *(const bf16x8*)&kp[((jt + 32) & (NC - 1)) * HDC];
        bf16x8 Bvn = *(const bf16x8*)&vp[((jt + 32) & (NC - 1)) + quad * 8];

        // early P(it-1) reads (latency hides under QK MFMA)
        bf16x8 Ap0 = *(const bf16x8*)&Pb[l15 * 40 + quad * 8];
        bf16x8 Ap1 = *(const bf16x8*)&Pb[(16 + l15) * 40 + quad * 8];

        f32x16 S = __builtin_amdgcn_mfma_f32_32x32x16_bf16(Ak, Bq, Z16, 0, 0, 0);

        __builtin_amdgcn_s_setprio(1);                // PV before exp: MFMA pipe
        Cc[0] = __builtin_amdgcn_mfma_f32_16x16x32_bf16(Ap0, Bvp, Cc[0], 0, 0, 0);
        Cw[0] = __builtin_amdgcn_mfma_f32_16x16x32_bf16(Ap0, ones.v, Cw[0], 0, 0, 0);
        Cc[1] = __builtin_amdgcn_mfma_f32_16x16x32_bf16(Ap1, Bvp, Cc[1], 0, 0, 0);
        Cw[1] = __builtin_amdgcn_mfma_f32_16x16x32_bf16(Ap1, ones.v, Cw[1], 0, 0, 0);
        __builtin_amdgcn_s_setprio(0);

        EXPTILE(&As[cur][0], Pa);                     // runs under PV MFMAs
        LDS_BARRIER();                                // P(it) + As[it+1] visible

        { short* t = Pa; Pa = Pb; Pb = t; }
        Ak = Akn; Bvp = Bv; Bv = Bvn;
    }

    // ---- epilogue: PV of the last tile (P(31) in Pb, V(31) in Bvp) ----
    {
        bf16x8 Ap0 = *(const bf16x8*)&Pb[l15 * 40 + quad * 8];
        bf16x8 Ap1 = *(const bf16x8*)&Pb[(16 + l15) * 40 + quad * 8];
        Cc[0] = __builtin_amdgcn_mfma_f32_16x16x32_bf16(Ap0, Bvp, Cc[0], 0, 0, 0);
        Cw[0] = __builtin_amdgcn_mfma_f32_16x16x32_bf16(Ap0, ones.v, Cw[0], 0, 0, 0);
        Cc[1] = __builtin_amdgcn_mfma_f32_16x16x32_bf16(Ap1, Bvp, Cc[1], 0, 0, 0);
        Cw[1] = __builtin_amdgcn_mfma_f32_16x16x32_bf16(Ap1, ones.v, Cw[1], 0, 0, 0);
    }

    // epilogue: ctx[q][d] = Cc/Cw, rows q = s*16+quad*4+r, col d = l15
#pragma unroll
    for (int s = 0; s < 2; ++s)
#pragma unroll
        for (int r = 0; r < 4; ++r) {
            float den = Cw[s][r];
            float rcp = den > 0.f ? 1.f / den : 0.f;
            int row = qt0 + s * 16 + quad * 4 + r;
            cb[xb + (size_t)row * DC + h * HDC + l15] = f2bf(Cc[s][r] * rcp);
        }
#undef EXPTILE
}

extern "C" void kernel_launch(void* const* d_in, const int* in_sizes, int n_in,
                              void* d_out, int out_size, void* d_ws, size_t ws_size,
                              hipStream_t stream)
{
    const float* x   = (const float*)d_in[0];
    const float* adj = (const float*)d_in[1];
    const float* Wq  = (const float*)d_in[2];
    const float* bq  = (const float*)d_in[3];
    const float* Wk  = (const float*)d_in[4];
    const float* bk  = (const float*)d_in[5];
    const float* Wv  = (const float*)d_in[6];
    const float* bv  = (const float*)d_in[7];
    const float* Wo  = (const float*)d_in[8];
    const float* bo  = (const float*)d_in[9];
    float* out = (float*)d_out;

    const size_t tok = (size_t)BTC * NC * DC;   // 2,097,152
    short* xbf  = (short*)d_ws;
    short* Wbf  = xbf  + tok;        // 4 * 16384
    short* qbuf = Wbf  + 65536;      // head-packed [bt][h][n][16]
    short* kbuf = qbuf + tok;        // head-packed [bt][h][n][16]
    short* vt   = kbuf + tok;        // transposed  [bt][d][n]
    short* cbuf = vt   + tok;

    prep_kernel<<<2112, 256, 0, stream>>>(x, Wq, Wk, Wv, Wo, xbf, Wbf);

    dim3 pgrid(256, 3);
    proj_qkv<<<pgrid, 256, 0, stream>>>(xbf, Wbf, bq, bk, bv, qbuf, kbuf, vt);

    dim3 agrid(32, 16, 2);
    attn_kernel<<<agrid, 256, 0, stream>>>(qbuf, kbuf, vt, adj, cbuf);

    proj_out<<<256, 256, 0, stream>>>(cbuf, Wbf + 3 * 16384, bo, out);
}

// Round 7
// 169.595 us; speedup vs baseline: 1.2092x; 1.0298x over previous
//
#include <hip/hip_runtime.h>
#include <hip/hip_bf16.h>

#define BTC 16
#define NC 1024
#define DC 128
#define HC 8
#define HDC 16

typedef __attribute__((ext_vector_type(8))) short bf16x8;   // 8 bf16 = 4 VGPR
typedef __attribute__((ext_vector_type(4))) float f32x4;    // MFMA C/D frag 16x16
typedef __attribute__((ext_vector_type(16))) float f32x16;  // MFMA C/D frag 32x32
typedef __attribute__((ext_vector_type(4))) short short4v;  // 4 bf16 = 2 VGPR

#if __has_builtin(__builtin_amdgcn_exp2f)
#define EXP2F(x) __builtin_amdgcn_exp2f(x)
#else
#define EXP2F(x) exp2f(x)
#endif

// q scale: 0.25 (1/sqrt(HD)) * log2(e)  -> attention uses exp2 directly
#define QSCALE 0.36067376022224085f

union PK2 { short4v s4; __hip_bfloat162 h2[2]; };
union PK8 { bf16x8 v; short s[8]; __hip_bfloat162 h2[4]; };

static __device__ inline short f2bf(float f) {               // RNE f32->bf16
    unsigned u = __builtin_bit_cast(unsigned, f);
    u += 0x7fffu + ((u >> 16) & 1u);
    return (short)(u >> 16);
}

// raw workgroup barrier: LDS-visibility only (lgkmcnt), keeps global register
// prefetches (vmcnt) in flight across the barrier (unlike __syncthreads).
#define LDS_BARRIER()                                              \
    do {                                                           \
        asm volatile("s_waitcnt lgkmcnt(0)" ::: "memory");         \
        __builtin_amdgcn_s_barrier();                              \
        asm volatile("" ::: "memory");                             \
    } while (0)

// ---------------- prep: fp32 -> bf16 for x and the 4 weight matrices --------
__global__ __launch_bounds__(256)
void prep_kernel(const float* __restrict__ x,
                 const float* __restrict__ Wq, const float* __restrict__ Wk,
                 const float* __restrict__ Wv, const float* __restrict__ Wo,
                 short* __restrict__ xbf, short* __restrict__ Wbf)
{
    int gid  = blockIdx.x * 256 + threadIdx.x;
    int base = gid * 4;
    const float* src;
    short* dst;
    if (base < 2097152) {                      // x: 16*1024*128
        src = x + base; dst = xbf + base;
    } else {
        int idx = base - 2097152;              // 0..65535 over 4 W's
        int w   = idx >> 14;
        int off = idx & 16383;
        src = ((w == 0) ? Wq : (w == 1) ? Wk : (w == 2) ? Wv : Wo) + off;
        dst = Wbf + w * 16384 + off;
    }
    float4 v = *(const float4*)src;
    PK2 pk;
    pk.h2[0] = __float22bfloat162_rn(make_float2(v.x, v.y));
    pk.h2[1] = __float22bfloat162_rn(make_float2(v.z, v.w));
    *(short4v*)dst = pk.s4;
}

// ---------------- MFMA projection, C = X @ W^T + b --------------------------
// block = 256 thr (4 waves), wave = 16 rows x 128 cols, K-loop 4x32.
// y = 0: q (scale QSCALE), 1: k — BOTH stored head-packed [bt][h][n][16] so
// the attention kernel's per-tile K load is one fully-coalesced 1KB wave load.
// y = 2: v stored transposed vt[bt][d][n] via LDS transpose -> 16B stores.
__global__ __launch_bounds__(256)
void proj_qkv(const short* __restrict__ xbf, const short* __restrict__ Wbf,
              const float* __restrict__ bq, const float* __restrict__ bk,
              const float* __restrict__ bv,
              short* __restrict__ qo, short* __restrict__ ko, short* __restrict__ vto)
{
    __shared__ short T[128 * 72];        // 18.4 KB transpose tile (y==2 only)

    const int y = blockIdx.y;
    const short* W = Wbf + y * 16384;
    const float* bias = (y == 0) ? bq : (y == 1) ? bk : bv;
    const float scale = (y == 0) ? QSCALE : 1.0f;

    const int tid  = threadIdx.x;
    const int wave = tid >> 6;
    const int lane = tid & 63;
    const int l15  = lane & 15;
    const int quad = lane >> 4;
    const int rowA = blockIdx.x * 64 + wave * 16;

    f32x4 acc[8];
#pragma unroll
    for (int t = 0; t < 8; ++t) acc[t] = (f32x4){0.f, 0.f, 0.f, 0.f};

#pragma unroll
    for (int kk = 0; kk < DC; kk += 32) {
        bf16x8 Af = *(const bf16x8*)&xbf[(size_t)(rowA + l15) * DC + kk + quad * 8];
#pragma unroll
        for (int t = 0; t < 8; ++t) {
            bf16x8 Bf = *(const bf16x8*)&W[(t * 16 + l15) * DC + kk + quad * 8];
            acc[t] = __builtin_amdgcn_mfma_f32_16x16x32_bf16(Af, Bf, acc[t], 0, 0, 0);
        }
    }

    if (y == 2) {
        // transpose through LDS: T[c][local_row], row stride 72 shorts (144 B,
        // 16-B aligned for b128 reads; bank-minimal b64 writes)
#pragma unroll
        for (int t = 0; t < 8; ++t) {
            int c = t * 16 + l15;
            float b = bias[c];
            PK2 pk;
            pk.h2[0] = __float22bfloat162_rn(make_float2(acc[t][0] + b, acc[t][1] + b));
            pk.h2[1] = __float22bfloat162_rn(make_float2(acc[t][2] + b, acc[t][3] + b));
            *(short4v*)&T[c * 72 + wave * 16 + quad * 4] = pk.s4;
        }
        __syncthreads();                  // y uniform per block: no divergence
        const int bt = blockIdx.x >> 4;
        const int n0 = (blockIdx.x * 64) & 1023;
        const int chunk = tid & 7;        // 8 chunks x 16 B = one 128-B d-row
        const int dr    = tid >> 3;       // 0..31
#pragma unroll
        for (int rep = 0; rep < 4; ++rep) {
            int d = rep * 32 + dr;
            bf16x8 u = *(const bf16x8*)&T[d * 72 + chunk * 8];
            *(bf16x8*)&vto[((size_t)bt * DC + d) * NC + n0 + chunk * 8] = u;
        }
    } else {
        short* dst = (y == 0) ? qo : ko;
#pragma unroll
        for (int t = 0; t < 8; ++t) {
            int c  = t * 16 + l15;
            int hh = c >> 4, dd = c & 15;
            float b = bias[c];
#pragma unroll
            for (int r = 0; r < 4; ++r) {
                int row = rowA + quad * 4 + r;       // = bt*1024 + n
                int btq = row >> 10, n = row & 1023;
                float val = (acc[t][r] + b) * scale;
                dst[(((size_t)btq * HC + hh) * NC + n) * HDC + dd] = f2bf(val);
            }
        }
    }
}

// out-projection: bf16 ctx in, fp32 out
__global__ __launch_bounds__(256)
void proj_out(const short* __restrict__ cbf, const short* __restrict__ Wobf,
              const float* __restrict__ bo, float* __restrict__ out)
{
    const int tid  = threadIdx.x;
    const int wave = tid >> 6;
    const int lane = tid & 63;
    const int l15  = lane & 15;
    const int quad = lane >> 4;
    const int rowA = blockIdx.x * 64 + wave * 16;

    f32x4 acc[8];
#pragma unroll
    for (int t = 0; t < 8; ++t) acc[t] = (f32x4){0.f, 0.f, 0.f, 0.f};

#pragma unroll
    for (int kk = 0; kk < DC; kk += 32) {
        bf16x8 Af = *(const bf16x8*)&cbf[(size_t)(rowA + l15) * DC + kk + quad * 8];
#pragma unroll
        for (int t = 0; t < 8; ++t) {
            bf16x8 Bf = *(const bf16x8*)&Wobf[(t * 16 + l15) * DC + kk + quad * 8];
            acc[t] = __builtin_amdgcn_mfma_f32_16x16x32_bf16(Af, Bf, acc[t], 0, 0, 0);
        }
    }

#pragma unroll
    for (int t = 0; t < 8; ++t) {
        int c = t * 16 + l15;
        float b = bo[c];
#pragma unroll
        for (int r = 0; r < 4; ++r) {
            int row = rowA + quad * 4 + r;
            out[(size_t)row * DC + c] = acc[t][r] + b;
        }
    }
}

// ---------------- MFMA attention: KVBLK=64, store-late, depth-2 -------------
// block = 256 thr = 4 waves = 4 heads; grid (32 qt, 16 bt, 2 hz) = 1024
// blocks -> 4 blocks/CU. Per wave (1 head, 32 q-rows), per 64-key group it
// (16 iterations, ONE barrier each — half of previous rounds):
//   2x [ S^T = K·Q (mfma_32x32x16, k=d=16); P = exp2(S^T)·adj -> bf16 ->
//        wave-private SINGLE-buffered Ps (reads of P(it-1) issue at top of
//        iter before these writes; same-pointer aliasing + in-order DS) ]
//   PV of group it-1: 4x b128 P-read + 8x mfma_16x16x32 (V frags + ones)
// The convoy fix (L3-hot round-6 dispatches proved attn is latency-bound,
// not HBM-bound): adj(it+1) is STORED LATE (end of iter, before the barrier),
// its global load issued in iter it-1 (~2 iterations of slack). After the
// barrier the stream starts with LDS P-reads and a register-resident QK MFMA
// — no vmcnt stall at the top of the iteration.
__global__ __launch_bounds__(256, 4)
void attn_kernel(const short* __restrict__ qh, const short* __restrict__ kh,
                 const short* __restrict__ vt, const float* __restrict__ adj,
                 short* __restrict__ cb)
{
    __shared__ float As[2][32 * 68];     // adj 32x64 tile dbuf, 17.4 KB
    __shared__ short Ps[4][32 * 72];     // wave-private P (64 keys), 18.4 KB

    const int tid  = threadIdx.x;
    const int wave = tid >> 6;
    const int lane = tid & 63;
    const int l31  = lane & 31;
    const int hi   = lane >> 5;
    const int l15  = lane & 15;
    const int quad = lane >> 4;
    const int bt   = blockIdx.y;
    const int qt0  = blockIdx.x * 32;
    const int h    = blockIdx.z * 4 + wave;

    const size_t xb = (size_t)bt * NC * DC;
    const size_t hb = ((size_t)bt * HC + h) * NC;    // head-packed row base

    // K A-frag: A[m=key=l31][k=d=hi*8+j]; per-subtile load = kp[key0*HDC]
    const short* kp = kh + (hb + l31) * HDC + hi * 8;
    // V B-frag: B[k=key=quad*8+j][n=d=l15]; per-subtile load = vp[key0+quad*8]
    const short* vp = vt + ((size_t)bt * DC + h * HDC + l15) * NC;
    // Q B-frag: B[k=d=hi*8+j][n=q=l31] (QSCALE folded at proj)
    const bf16x8 Bq = *(const bf16x8*)&qh[(hb + qt0 + l31) * HDC + hi * 8];

    // adj staging: 256 thr x 2 float4 cover the 32x64 f32 tile, coalesced
    const int arow = tid >> 3;            // 0..31
    const int acolf = (tid & 7) * 8;      // float col 0,8,..,56
    const float* aptr = adj + (size_t)bt * NC * NC + (size_t)(qt0 + arow) * NC + acolf;
    const int awoff = arow * 68 + acolf;  // 16-B aligned (272,32 both %16==0)

    PK8 ones;
#pragma unroll
    for (int j = 0; j < 8; ++j) ones.s[j] = (short)0x3F80;   // bf16 1.0

    f32x16 Z16;
#pragma unroll
    for (int i = 0; i < 16; ++i) Z16[i] = 0.f;               // hoisted zero C

    f32x4 Cc[2], Cw[2];
#pragma unroll
    for (int s = 0; s < 2; ++s) {
        Cc[s] = (f32x4){0.f, 0.f, 0.f, 0.f};
        Cw[s] = (f32x4){0.f, 0.f, 0.f, 0.f};
    }

    short* Pw = &Ps[wave][0];            // single-buffered wave-private P

    // P = exp2(S^T)*adj -> bf16 -> Pw (key-half H2 = 0 or 32).
    // S reg r: key = H2 + (r&3) + 8*(r>>2) + 4*hi; As col = H2 + t*8 + hi*4.
#define EXPTILE(S, ASB, H2)                                                   \
    do {                                                                      \
        const float* asb = (ASB) + l31 * 68 + (H2) + hi * 4;                  \
        float4 a0 = *(const float4*)&asb[0];                                  \
        float4 a1 = *(const float4*)&asb[8];                                  \
        float4 a2 = *(const float4*)&asb[16];                                 \
        float4 a3 = *(const float4*)&asb[24];                                 \
        short* pd = Pw + l31 * 72 + (H2) + hi * 4;                            \
        PK2 pk;                                                               \
        pk.h2[0] = __float22bfloat162_rn(                                     \
            make_float2(EXP2F(S[0]) * a0.x, EXP2F(S[1]) * a0.y));             \
        pk.h2[1] = __float22bfloat162_rn(                                     \
            make_float2(EXP2F(S[2]) * a0.z, EXP2F(S[3]) * a0.w));             \
        *(short4v*)&pd[0] = pk.s4;                                            \
        pk.h2[0] = __float22bfloat162_rn(                                     \
            make_float2(EXP2F(S[4]) * a1.x, EXP2F(S[5]) * a1.y));             \
        pk.h2[1] = __float22bfloat162_rn(                                     \
            make_float2(EXP2F(S[6]) * a1.z, EXP2F(S[7]) * a1.w));             \
        *(short4v*)&pd[8] = pk.s4;                                            \
        pk.h2[0] = __float22bfloat162_rn(                                     \
            make_float2(EXP2F(S[8]) * a2.x, EXP2F(S[9]) * a2.y));             \
        pk.h2[1] = __float22bfloat162_rn(                                     \
            make_float2(EXP2F(S[10]) * a2.z, EXP2F(S[11]) * a2.w));           \
        *(short4v*)&pd[16] = pk.s4;                                           \
        pk.h2[0] = __float22bfloat162_rn(                                     \
            make_float2(EXP2F(S[12]) * a3.x, EXP2F(S[13]) * a3.y));           \
        pk.h2[1] = __float22bfloat162_rn(                                     \
            make_float2(EXP2F(S[14]) * a3.z, EXP2F(S[15]) * a3.w));           \
        *(short4v*)&pd[24] = pk.s4;                                           \
    } while (0)

    // ---- prologue: stage adj(0), prefetch adj(1), K(0) ----
    float4 p0a = *(const float4*)&aptr[0];
    float4 p0b = *(const float4*)&aptr[4];            // adj(0)
    float4 ara = *(const float4*)&aptr[64];
    float4 arb = *(const float4*)&aptr[68];           // adj(1)
    bf16x8 AkA = *(const bf16x8*)&kp[0];              // K(0) lo
    bf16x8 AkB = *(const bf16x8*)&kp[32 * HDC];       // K(0) hi

    *(float4*)((char*)&As[0][0] + awoff * 4)      = p0a;
    *(float4*)((char*)&As[0][0] + awoff * 4 + 16) = p0b;
    LDS_BARRIER();                                    // adj(0) visible

    // ---- iter 0 (group 0): QK + exp only, PV lags one group ----
    {
        float4 arna = *(const float4*)&aptr[128];     // adj(2)
        float4 arnb = *(const float4*)&aptr[132];
        bf16x8 AkAn = *(const bf16x8*)&kp[64 * HDC];  // K(1)
        bf16x8 AkBn = *(const bf16x8*)&kp[96 * HDC];

        f32x16 S0 = __builtin_amdgcn_mfma_f32_32x32x16_bf16(AkA, Bq, Z16, 0, 0, 0);
        EXPTILE(S0, &As[0][0], 0);
        f32x16 S1 = __builtin_amdgcn_mfma_f32_32x32x16_bf16(AkB, Bq, Z16, 0, 0, 0);
        EXPTILE(S1, &As[0][0], 32);

        *(float4*)((char*)&As[1][0] + awoff * 4)      = ara;   // adj(1) late
        *(float4*)((char*)&As[1][0] + awoff * 4 + 16) = arb;
        LDS_BARRIER();                                // P(0) + adj(1) visible

        ara = arna; arb = arnb; AkA = AkAn; AkB = AkBn;
    }

    for (int it = 1; it < 16; ++it) {
        const int jt  = it * 64;
        const int cur = it & 1;                       // As[cur] holds adj(it)

        // top: independent issues only (no vmcnt stall — K is in registers)
        bf16x8 ApA0 = *(const bf16x8*)&Pw[l15 * 72 + quad * 8];
        bf16x8 ApA1 = *(const bf16x8*)&Pw[(16 + l15) * 72 + quad * 8];
        bf16x8 ApB0 = *(const bf16x8*)&Pw[l15 * 72 + 32 + quad * 8];
        bf16x8 ApB1 = *(const bf16x8*)&Pw[(16 + l15) * 72 + 32 + quad * 8];
        bf16x8 BvpA = *(const bf16x8*)&vp[jt - 64 + quad * 8];   // V(it-1)
        bf16x8 BvpB = *(const bf16x8*)&vp[jt - 32 + quad * 8];
        const int nj2 = (jt + 128) & (NC - 1);
        float4 arna = *(const float4*)&aptr[nj2];                // adj(it+2)
        float4 arnb = *(const float4*)&aptr[nj2 + 4];
        bf16x8 AkAn = *(const bf16x8*)&kp[((jt + 64) & (NC - 1)) * HDC];
        bf16x8 AkBn = *(const bf16x8*)&kp[((jt + 96) & (NC - 1)) * HDC];

        f32x16 S0 = __builtin_amdgcn_mfma_f32_32x32x16_bf16(AkA, Bq, Z16, 0, 0, 0);

        __builtin_amdgcn_s_setprio(1);                // PV of group it-1
        Cc[0] = __builtin_amdgcn_mfma_f32_16x16x32_bf16(ApA0, BvpA, Cc[0], 0, 0, 0);
        Cw[0] = __builtin_amdgcn_mfma_f32_16x16x32_bf16(ApA0, ones.v, Cw[0], 0, 0, 0);
        Cc[1] = __builtin_amdgcn_mfma_f32_16x16x32_bf16(ApA1, BvpA, Cc[1], 0, 0, 0);
        Cw[1] = __builtin_amdgcn_mfma_f32_16x16x32_bf16(ApA1, ones.v, Cw[1], 0, 0, 0);
        Cc[0] = __builtin_amdgcn_mfma_f32_16x16x32_bf16(ApB0, BvpB, Cc[0], 0, 0, 0);
        Cw[0] = __builtin_amdgcn_mfma_f32_16x16x32_bf16(ApB0, ones.v, Cw[0], 0, 0, 0);
        Cc[1] = __builtin_amdgcn_mfma_f32_16x16x32_bf16(ApB1, BvpB, Cc[1], 0, 0, 0);
        Cw[1] = __builtin_amdgcn_mfma_f32_16x16x32_bf16(ApB1, ones.v, Cw[1], 0, 0, 0);
        __builtin_amdgcn_s_setprio(0);

        EXPTILE(S0, &As[cur][0], 0);                  // overwrites Pw lo half
        f32x16 S1 = __builtin_amdgcn_mfma_f32_32x32x16_bf16(AkB, Bq, Z16, 0, 0, 0);
        EXPTILE(S1, &As[cur][0], 32);                 // overwrites Pw hi half

        *(float4*)((char*)&As[cur ^ 1][0] + awoff * 4)      = ara;  // adj(it+1)
        *(float4*)((char*)&As[cur ^ 1][0] + awoff * 4 + 16) = arb;  // store-late
        LDS_BARRIER();                                // P(it) + adj(it+1) visible

        ara = arna; arb = arnb; AkA = AkAn; AkB = AkBn;
    }

    // ---- epilogue: PV of group 15 ----
    {
        bf16x8 ApA0 = *(const bf16x8*)&Pw[l15 * 72 + quad * 8];
        bf16x8 ApA1 = *(const bf16x8*)&Pw[(16 + l15) * 72 + quad * 8];
        bf16x8 ApB0 = *(const bf16x8*)&Pw[l15 * 72 + 32 + quad * 8];
        bf16x8 ApB1 = *(const bf16x8*)&Pw[(16 + l15) * 72 + 32 + quad * 8];
        bf16x8 BvpA = *(const bf16x8*)&vp[960 + quad * 8];
        bf16x8 BvpB = *(const bf16x8*)&vp[992 + quad * 8];
        Cc[0] = __builtin_amdgcn_mfma_f32_16x16x32_bf16(ApA0, BvpA, Cc[0], 0, 0, 0);
        Cw[0] = __builtin_amdgcn_mfma_f32_16x16x32_bf16(ApA0, ones.v, Cw[0], 0, 0, 0);
        Cc[1] = __builtin_amdgcn_mfma_f32_16x16x32_bf16(ApA1, BvpA, Cc[1], 0, 0, 0);
        Cw[1] = __builtin_amdgcn_mfma_f32_16x16x32_bf16(ApA1, ones.v, Cw[1], 0, 0, 0);
        Cc[0] = __builtin_amdgcn_mfma_f32_16x16x32_bf16(ApB0, BvpB, Cc[0], 0, 0, 0);
        Cw[0] = __builtin_amdgcn_mfma_f32_16x16x32_bf16(ApB0, ones.v, Cw[0], 0, 0, 0);
        Cc[1] = __builtin_amdgcn_mfma_f32_16x16x32_bf16(ApB1, BvpB, Cc[1], 0, 0, 0);
        Cw[1] = __builtin_amdgcn_mfma_f32_16x16x32_bf16(ApB1, ones.v, Cw[1], 0, 0, 0);
    }

    // epilogue: ctx[q][d] = Cc/Cw, rows q = s*16+quad*4+r, col d = l15
#pragma unroll
    for (int s = 0; s < 2; ++s)
#pragma unroll
        for (int r = 0; r < 4; ++r) {
            float den = Cw[s][r];
            float rcp = den > 0.f ? 1.f / den : 0.f;
            int row = qt0 + s * 16 + quad * 4 + r;
            cb[xb + (size_t)row * DC + h * HDC + l15] = f2bf(Cc[s][r] * rcp);
        }
#undef EXPTILE
}

extern "C" void kernel_launch(void* const* d_in, const int* in_sizes, int n_in,
                              void* d_out, int out_size, void* d_ws, size_t ws_size,
                              hipStream_t stream)
{
    const float* x   = (const float*)d_in[0];
    const float* adj = (const float*)d_in[1];
    const float* Wq  = (const float*)d_in[2];
    const float* bq  = (const float*)d_in[3];
    const float* Wk  = (const float*)d_in[4];
    const float* bk  = (const float*)d_in[5];
    const float* Wv  = (const float*)d_in[6];
    const float* bv  = (const float*)d_in[7];
    const float* Wo  = (const float*)d_in[8];
    const float* bo  = (const float*)d_in[9];
    float* out = (float*)d_out;

    const size_t tok = (size_t)BTC * NC * DC;   // 2,097,152
    short* xbf  = (short*)d_ws;
    short* Wbf  = xbf  + tok;        // 4 * 16384
    short* qbuf = Wbf  + 65536;      // head-packed [bt][h][n][16]
    short* kbuf = qbuf + tok;        // head-packed [bt][h][n][16]
    short* vt   = kbuf + tok;        // transposed  [bt][d][n]
    short* cbuf = vt   + tok;

    prep_kernel<<<2112, 256, 0, stream>>>(x, Wq, Wk, Wv, Wo, xbf, Wbf);

    dim3 pgrid(256, 3);
    proj_qkv<<<pgrid, 256, 0, stream>>>(xbf, Wbf, bq, bk, bv, qbuf, kbuf, vt);

    dim3 agrid(32, 16, 2);
    attn_kernel<<<agrid, 256, 0, stream>>>(qbuf, kbuf, vt, adj, cbuf);

    proj_out<<<256, 256, 0, stream>>>(cbuf, Wbf + 3 * 16384, bo, out);
}